// Round 1
// baseline (105.495 us; speedup 1.0000x reference)
//
#include <hip/hip_runtime.h>
#include <hip/hip_bf16.h>

// Problem constants
#define BATCH   4096
#define TWO_B   8192
#define DIM     128
#define INV_TEMP 2.0f      // 1/TEMP, TEMP=0.5

typedef __attribute__((ext_vector_type(8))) short bf16x8;   // 8 bf16 = 4 VGPRs
typedef __attribute__((ext_vector_type(4))) float f32x4;

// Workspace layout (bytes):
//   zb      : __hip_bfloat16[TWO_B*DIM]  [0, 2097152)
//   rowsum  : float[TWO_B]               [2097152, 2130 - ...)
//   possum  : float[1]                   right after rowsum
#define ZB_BYTES   (TWO_B * DIM * 2)
#define RS_OFFSET  ZB_BYTES
#define PS_OFFSET  (RS_OFFSET + TWO_B * 4)

// ---------------------------------------------------------------------------
// Kernel 1: L2-normalize each row of zi/zj (fp32 in) -> bf16 z rows in ws.
// One wave per row; lane handles 2 of the 128 elements.
// ---------------------------------------------------------------------------
__global__ __launch_bounds__(256) void k_normalize(const float* __restrict__ zi,
                                                   const float* __restrict__ zj,
                                                   __hip_bfloat16* __restrict__ zb) {
    int w = threadIdx.x >> 6;
    int lane = threadIdx.x & 63;
    int r = blockIdx.x * 4 + w;                       // [0, TWO_B)
    const float* src = (r < BATCH) ? (zi + (size_t)r * DIM)
                                   : (zj + (size_t)(r - BATCH) * DIM);
    float2 v = *reinterpret_cast<const float2*>(src + lane * 2);
    float ss = v.x * v.x + v.y * v.y;
    #pragma unroll
    for (int m = 1; m < 64; m <<= 1) ss += __shfl_xor(ss, m, 64);
    float n = sqrtf(ss);
    float inv = 1.0f / fmaxf(n, 1e-12f);
    __hip_bfloat162 h2;
    h2.x = __float2bfloat16(v.x * inv);
    h2.y = __float2bfloat16(v.y * inv);
    *reinterpret_cast<__hip_bfloat162*>(zb + (size_t)r * DIM + lane * 2) = h2;
}

// ---------------------------------------------------------------------------
// Kernel 2: tiled similarity + fused exp/row-sum.
// Grid: (TWO_B/128) * CS blocks, 256 threads (4 waves, 2x2 wave grid).
// Each block: rows [rowBlk*128, +128), cols [split*1024, +1024) in 8 col-tiles.
// LDS tiles are XOR-swizzled (byte blk16 ^= row&7) to avoid the D=128
// 16-way ds_read_b128 bank conflict (G4).
// ---------------------------------------------------------------------------
#define CS 8

__global__ __launch_bounds__(256) void k_sim(const __hip_bfloat16* __restrict__ zb,
                                             float* __restrict__ rowsum) {
    __shared__ unsigned short As[128 * 128];   // 32 KB
    __shared__ unsigned short Bs[128 * 128];   // 32 KB

    const int t = threadIdx.x;
    const int rowBlk = blockIdx.x / CS;
    const int split  = blockIdx.x % CS;
    const int rowBase = rowBlk * 128;

    // ---- stage A tile (reused across all 8 col-tiles) ----
    #pragma unroll
    for (int it = 0; it < 8; ++it) {
        int chunk = t + it * 256;          // 0..2047, each = 16 B
        int row = chunk >> 4;
        int blk = chunk & 15;
        bf16x8 v = *reinterpret_cast<const bf16x8*>(zb + (size_t)(rowBase + row) * DIM + blk * 8);
        int sb = blk ^ (row & 7);
        *reinterpret_cast<bf16x8*>(reinterpret_cast<char*>(As) + row * 256 + sb * 16) = v;
    }

    const int w    = t >> 6;
    const int lane = t & 63;
    const int wr = w >> 1, wc = w & 1;
    const int lo = lane & 15, hi = lane >> 4;

    float psum[4][4];
    #pragma unroll
    for (int i = 0; i < 4; ++i)
        #pragma unroll
        for (int p = 0; p < 4; ++p) psum[i][p] = 0.0f;

    for (int ct = 0; ct < 8; ++ct) {
        const int colBase = split * 1024 + ct * 128;
        __syncthreads();   // prior compute done before overwriting Bs
        #pragma unroll
        for (int it = 0; it < 8; ++it) {
            int chunk = t + it * 256;
            int row = chunk >> 4;
            int blk = chunk & 15;
            bf16x8 v = *reinterpret_cast<const bf16x8*>(zb + (size_t)(colBase + row) * DIM + blk * 8);
            int sb = blk ^ (row & 7);
            *reinterpret_cast<bf16x8*>(reinterpret_cast<char*>(Bs) + row * 256 + sb * 16) = v;
        }
        __syncthreads();

        f32x4 acc[4][4];
        #pragma unroll
        for (int i = 0; i < 4; ++i)
            #pragma unroll
            for (int j = 0; j < 4; ++j) acc[i][j] = (f32x4){0.f, 0.f, 0.f, 0.f};

        #pragma unroll
        for (int ks = 0; ks < 4; ++ks) {
            bf16x8 a[4], b[4];
            #pragma unroll
            for (int i = 0; i < 4; ++i) {
                int rA = wr * 64 + i * 16 + lo;
                int ba = (ks * 4 + hi) ^ (rA & 7);
                a[i] = *reinterpret_cast<const bf16x8*>(
                    reinterpret_cast<const char*>(As) + rA * 256 + ba * 16);
                int rB = wc * 64 + i * 16 + lo;
                int bb = (ks * 4 + hi) ^ (rB & 7);
                b[i] = *reinterpret_cast<const bf16x8*>(
                    reinterpret_cast<const char*>(Bs) + rB * 256 + bb * 16);
            }
            #pragma unroll
            for (int i = 0; i < 4; ++i)
                #pragma unroll
                for (int j = 0; j < 4; ++j)
                    acc[i][j] = __builtin_amdgcn_mfma_f32_16x16x32_bf16(a[i], b[j], acc[i][j], 0, 0, 0);
        }

        // fused epilogue: S = acc * INV_TEMP; exclude self-diagonal; exp; row partial sums
        // C/D layout (m89): col = lane&15, row = (lane>>4)*4 + reg
        #pragma unroll
        for (int i = 0; i < 4; ++i) {
            int grBase = rowBase + wr * 64 + i * 16 + hi * 4;
            #pragma unroll
            for (int p = 0; p < 4; ++p) {
                int gr = grBase + p;
                float s = 0.0f;
                #pragma unroll
                for (int j = 0; j < 4; ++j) {
                    int gc = colBase + wc * 64 + j * 16 + lo;
                    float e = __expf(acc[i][j][p] * INV_TEMP);
                    s += (gr == gc) ? 0.0f : e;
                }
                psum[i][p] += s;
            }
        }
    }

    // reduce across the 16 lanes (lo) holding different columns, then atomicAdd.
    #pragma unroll
    for (int i = 0; i < 4; ++i) {
        #pragma unroll
        for (int p = 0; p < 4; ++p) {
            float s = psum[i][p];
            s += __shfl_xor(s, 1, 64);
            s += __shfl_xor(s, 2, 64);
            s += __shfl_xor(s, 4, 64);
            s += __shfl_xor(s, 8, 64);
            if (lo == 0)
                atomicAdd(&rowsum[rowBase + wr * 64 + i * 16 + hi * 4 + p], s);
        }
    }
}

// ---------------------------------------------------------------------------
// Kernel 3: sum of paired-diagonal dots: possum = sum_{r<B} dot(z[r], z[r+B])
// ---------------------------------------------------------------------------
__global__ __launch_bounds__(256) void k_pos(const __hip_bfloat16* __restrict__ zb,
                                             float* __restrict__ possum) {
    int w = threadIdx.x >> 6;
    int lane = threadIdx.x & 63;
    int r = blockIdx.x * 4 + w;                      // [0, BATCH)
    const __hip_bfloat16* a = zb + (size_t)r * DIM;
    const __hip_bfloat16* b = zb + (size_t)(r + BATCH) * DIM;
    float s = 0.0f;
    #pragma unroll
    for (int q = 0; q < 2; ++q) {
        int idx = lane * 2 + q;
        s += __bfloat162float(a[idx]) * __bfloat162float(b[idx]);
    }
    #pragma unroll
    for (int m = 1; m < 64; m <<= 1) s += __shfl_xor(s, m, 64);
    if (lane == 0) atomicAdd(possum, s);
}

// ---------------------------------------------------------------------------
// Kernel 4: loss = (sum_r log(rowsum[r]) - 2*INV_TEMP*possum) / TWO_B
// ---------------------------------------------------------------------------
__global__ __launch_bounds__(256) void k_final(const float* __restrict__ rowsum,
                                               const float* __restrict__ possum,
                                               float* __restrict__ out) {
    __shared__ float red[256];
    float s = 0.0f;
    for (int r = threadIdx.x; r < TWO_B; r += 256) s += logf(rowsum[r]);
    red[threadIdx.x] = s;
    __syncthreads();
    #pragma unroll
    for (int off = 128; off > 0; off >>= 1) {
        if (threadIdx.x < off) red[threadIdx.x] += red[threadIdx.x + off];
        __syncthreads();
    }
    if (threadIdx.x == 0)
        out[0] = (red[0] - 2.0f * INV_TEMP * possum[0]) / (float)TWO_B;
}

// ---------------------------------------------------------------------------
extern "C" void kernel_launch(void* const* d_in, const int* in_sizes, int n_in,
                              void* d_out, int out_size, void* d_ws, size_t ws_size,
                              hipStream_t stream) {
    const float* zi = (const float*)d_in[0];
    const float* zj = (const float*)d_in[1];
    float* out = (float*)d_out;

    char* ws = (char*)d_ws;
    __hip_bfloat16* zb = (__hip_bfloat16*)ws;
    float* rowsum = (float*)(ws + RS_OFFSET);
    float* possum = (float*)(ws + PS_OFFSET);

    // zero rowsum + possum (must happen every call; harness doesn't re-poison)
    hipMemsetAsync(ws + RS_OFFSET, 0, (TWO_B + 1) * sizeof(float), stream);

    k_normalize<<<TWO_B / 4, 256, 0, stream>>>(zi, zj, zb);
    k_sim<<<(TWO_B / 128) * CS, 256, 0, stream>>>(zb, rowsum);
    k_pos<<<BATCH / 4, 256, 0, stream>>>(zb, possum);
    k_final<<<1, 256, 0, stream>>>(rowsum, possum, out);
}

// Round 2
// 62.726 us; speedup vs baseline: 1.6818x; 1.6818x over previous
//
#include <hip/hip_runtime.h>
#include <hip/hip_bf16.h>

// Problem constants
#define BATCH   4096
#define TWO_B   8192
#define DIM     128
#define INV_TEMP 2.0f      // 1/TEMP, TEMP=0.5

typedef __attribute__((ext_vector_type(8))) short bf16x8;   // 8 bf16 = 4 VGPRs
typedef __attribute__((ext_vector_type(4))) float f32x4;

// Workspace layout (bytes):
//   zb      : __hip_bfloat16[TWO_B*DIM]  [0, 2097152)
//   rowsum  : float[TWO_B]
//   possum  : float[1]
#define ZB_BYTES   (TWO_B * DIM * 2)
#define RS_OFFSET  ZB_BYTES
#define PS_OFFSET  (RS_OFFSET + TWO_B * 4)

// ---------------------------------------------------------------------------
// Kernel 1: L2-normalize rows of zi AND zj (paired), write bf16 z rows, and
// accumulate possum = sum_r dot(zi_n[r], zj_n[r]) with ONE atomic per block.
// Wave w handles pair-row r: zi[r] -> zb[r], zj[r] -> zb[r+BATCH].
// ---------------------------------------------------------------------------
__global__ __launch_bounds__(256) void k_normalize(const float* __restrict__ zi,
                                                   const float* __restrict__ zj,
                                                   __hip_bfloat16* __restrict__ zb,
                                                   float* __restrict__ possum) {
    int w = threadIdx.x >> 6;
    int lane = threadIdx.x & 63;
    int r = blockIdx.x * 4 + w;                       // [0, BATCH)

    float2 vi = *reinterpret_cast<const float2*>(zi + (size_t)r * DIM + lane * 2);
    float2 vj = *reinterpret_cast<const float2*>(zj + (size_t)r * DIM + lane * 2);
    float ssi = vi.x * vi.x + vi.y * vi.y;
    float ssj = vj.x * vj.x + vj.y * vj.y;
    #pragma unroll
    for (int m = 1; m < 64; m <<= 1) {
        ssi += __shfl_xor(ssi, m, 64);
        ssj += __shfl_xor(ssj, m, 64);
    }
    float invi = 1.0f / fmaxf(sqrtf(ssi), 1e-12f);
    float invj = 1.0f / fmaxf(sqrtf(ssj), 1e-12f);

    float nix = vi.x * invi, niy = vi.y * invi;
    float njx = vj.x * invj, njy = vj.y * invj;

    __hip_bfloat162 hi2, hj2;
    hi2.x = __float2bfloat16(nix);
    hi2.y = __float2bfloat16(niy);
    hj2.x = __float2bfloat16(njx);
    hj2.y = __float2bfloat16(njy);
    *reinterpret_cast<__hip_bfloat162*>(zb + (size_t)r * DIM + lane * 2) = hi2;
    *reinterpret_cast<__hip_bfloat162*>(zb + (size_t)(r + BATCH) * DIM + lane * 2) = hj2;

    // paired-diagonal dot in fp32
    float d = nix * njx + niy * njy;
    #pragma unroll
    for (int m = 1; m < 64; m <<= 1) d += __shfl_xor(d, m, 64);

    __shared__ float red[4];
    if (lane == 0) red[w] = d;
    __syncthreads();
    if (threadIdx.x == 0)
        atomicAdd(possum, red[0] + red[1] + red[2] + red[3]);
}

// ---------------------------------------------------------------------------
// Kernel 2: tiled similarity + fused exp/row-sum.
// Grid: (TWO_B/128) * CS blocks, 256 threads (4 waves, 2x2 wave grid).
// Each block: rows [rowBlk*128, +128), cols [split*1024, +1024) in 8 col-tiles.
// LDS tiles are XOR-swizzled (byte blk16 ^= row&7) to avoid the D=128
// 16-way ds_read_b128 bank conflict (G4).
// ---------------------------------------------------------------------------
#define CS 8

__global__ __launch_bounds__(256) void k_sim(const __hip_bfloat16* __restrict__ zb,
                                             float* __restrict__ rowsum) {
    __shared__ unsigned short As[128 * 128];   // 32 KB
    __shared__ unsigned short Bs[128 * 128];   // 32 KB

    const int t = threadIdx.x;
    const int rowBlk = blockIdx.x / CS;
    const int split  = blockIdx.x % CS;
    const int rowBase = rowBlk * 128;

    // ---- stage A tile (reused across all 8 col-tiles) ----
    #pragma unroll
    for (int it = 0; it < 8; ++it) {
        int chunk = t + it * 256;          // 0..2047, each = 16 B
        int row = chunk >> 4;
        int blk = chunk & 15;
        bf16x8 v = *reinterpret_cast<const bf16x8*>(zb + (size_t)(rowBase + row) * DIM + blk * 8);
        int sb = blk ^ (row & 7);
        *reinterpret_cast<bf16x8*>(reinterpret_cast<char*>(As) + row * 256 + sb * 16) = v;
    }

    const int w    = t >> 6;
    const int lane = t & 63;
    const int wr = w >> 1, wc = w & 1;
    const int lo = lane & 15, hi = lane >> 4;

    float psum[4][4];
    #pragma unroll
    for (int i = 0; i < 4; ++i)
        #pragma unroll
        for (int p = 0; p < 4; ++p) psum[i][p] = 0.0f;

    for (int ct = 0; ct < 8; ++ct) {
        const int colBase = split * 1024 + ct * 128;
        __syncthreads();   // prior compute done before overwriting Bs
        #pragma unroll
        for (int it = 0; it < 8; ++it) {
            int chunk = t + it * 256;
            int row = chunk >> 4;
            int blk = chunk & 15;
            bf16x8 v = *reinterpret_cast<const bf16x8*>(zb + (size_t)(colBase + row) * DIM + blk * 8);
            int sb = blk ^ (row & 7);
            *reinterpret_cast<bf16x8*>(reinterpret_cast<char*>(Bs) + row * 256 + sb * 16) = v;
        }
        __syncthreads();

        f32x4 acc[4][4];
        #pragma unroll
        for (int i = 0; i < 4; ++i)
            #pragma unroll
            for (int j = 0; j < 4; ++j) acc[i][j] = (f32x4){0.f, 0.f, 0.f, 0.f};

        #pragma unroll
        for (int ks = 0; ks < 4; ++ks) {
            bf16x8 a[4], b[4];
            #pragma unroll
            for (int i = 0; i < 4; ++i) {
                int rA = wr * 64 + i * 16 + lo;
                int ba = (ks * 4 + hi) ^ (rA & 7);
                a[i] = *reinterpret_cast<const bf16x8*>(
                    reinterpret_cast<const char*>(As) + rA * 256 + ba * 16);
                int rB = wc * 64 + i * 16 + lo;
                int bb = (ks * 4 + hi) ^ (rB & 7);
                b[i] = *reinterpret_cast<const bf16x8*>(
                    reinterpret_cast<const char*>(Bs) + rB * 256 + bb * 16);
            }
            #pragma unroll
            for (int i = 0; i < 4; ++i)
                #pragma unroll
                for (int j = 0; j < 4; ++j)
                    acc[i][j] = __builtin_amdgcn_mfma_f32_16x16x32_bf16(a[i], b[j], acc[i][j], 0, 0, 0);
        }

        // fused epilogue: S = acc * INV_TEMP; exclude self-diagonal; exp; row partial sums
        // C/D layout (m89): col = lane&15, row = (lane>>4)*4 + reg
        #pragma unroll
        for (int i = 0; i < 4; ++i) {
            int grBase = rowBase + wr * 64 + i * 16 + hi * 4;
            #pragma unroll
            for (int p = 0; p < 4; ++p) {
                int gr = grBase + p;
                float s = 0.0f;
                #pragma unroll
                for (int j = 0; j < 4; ++j) {
                    int gc = colBase + wc * 64 + j * 16 + lo;
                    float e = __expf(acc[i][j][p] * INV_TEMP);
                    s += (gr == gc) ? 0.0f : e;
                }
                psum[i][p] += s;
            }
        }
    }

    // reduce across the 16 lanes (lo) holding different columns, then atomicAdd.
    #pragma unroll
    for (int i = 0; i < 4; ++i) {
        #pragma unroll
        for (int p = 0; p < 4; ++p) {
            float s = psum[i][p];
            s += __shfl_xor(s, 1, 64);
            s += __shfl_xor(s, 2, 64);
            s += __shfl_xor(s, 4, 64);
            s += __shfl_xor(s, 8, 64);
            if (lo == 0)
                atomicAdd(&rowsum[rowBase + wr * 64 + i * 16 + hi * 4 + p], s);
        }
    }
}

// ---------------------------------------------------------------------------
// Kernel 3: loss = (sum_r log(rowsum[r]) - 2*INV_TEMP*possum) / TWO_B
// ---------------------------------------------------------------------------
__global__ __launch_bounds__(256) void k_final(const float* __restrict__ rowsum,
                                               const float* __restrict__ possum,
                                               float* __restrict__ out) {
    __shared__ float red[256];
    float s = 0.0f;
    for (int r = threadIdx.x; r < TWO_B; r += 256) s += logf(rowsum[r]);
    red[threadIdx.x] = s;
    __syncthreads();
    #pragma unroll
    for (int off = 128; off > 0; off >>= 1) {
        if (threadIdx.x < off) red[threadIdx.x] += red[threadIdx.x + off];
        __syncthreads();
    }
    if (threadIdx.x == 0)
        out[0] = (red[0] - 2.0f * INV_TEMP * possum[0]) / (float)TWO_B;
}

// ---------------------------------------------------------------------------
extern "C" void kernel_launch(void* const* d_in, const int* in_sizes, int n_in,
                              void* d_out, int out_size, void* d_ws, size_t ws_size,
                              hipStream_t stream) {
    const float* zi = (const float*)d_in[0];
    const float* zj = (const float*)d_in[1];
    float* out = (float*)d_out;

    char* ws = (char*)d_ws;
    __hip_bfloat16* zb = (__hip_bfloat16*)ws;
    float* rowsum = (float*)(ws + RS_OFFSET);
    float* possum = (float*)(ws + PS_OFFSET);

    // zero rowsum + possum (must happen every call; harness doesn't re-poison)
    hipMemsetAsync(ws + RS_OFFSET, 0, (TWO_B + 1) * sizeof(float), stream);

    k_normalize<<<BATCH / 4, 256, 0, stream>>>(zi, zj, zb, possum);
    k_sim<<<(TWO_B / 128) * CS, 256, 0, stream>>>(zb, rowsum);
    k_final<<<1, 256, 0, stream>>>(rowsum, possum, out);
}

// Round 5
// 50.823 us; speedup vs baseline: 2.0757x; 1.2342x over previous
//
#include <hip/hip_runtime.h>
#include <hip/hip_bf16.h>

// Problem constants
#define BATCH   4096
#define TWO_B   8192
#define DIM     128
#define INV_TEMP 2.0f      // 1/TEMP, TEMP=0.5
#define EXP_SCALE (2.0f * 1.442695040888963f)   // INV_TEMP * log2(e)

typedef __attribute__((ext_vector_type(8))) short bf16x8;   // 8 bf16 = 4 VGPRs
typedef __attribute__((ext_vector_type(4))) float f32x4;

#define CS 8           // column splits in k_sim
#define NPART (CS * 2) // partials per row (split x wc)

// Workspace layout (bytes) — everything is write-before-read, no zeroing needed:
//   zb : __hip_bfloat16[TWO_B*DIM]      [0, 2097152)
//   rs : float[NPART][TWO_B]            [2097152, +524288)
//   ps : float[1024]                    [2621440, +4096)
#define ZB_BYTES   (TWO_B * DIM * 2)
#define RS_OFFSET  ZB_BYTES
#define PS_OFFSET  (RS_OFFSET + NPART * TWO_B * 4)

// ---------------------------------------------------------------------------
// Kernel 1: L2-normalize rows of zi AND zj (paired), write bf16 z rows, and
// write per-block partial of possum = sum_r dot(zi_n[r], zj_n[r]).
// ---------------------------------------------------------------------------
__global__ __launch_bounds__(256) void k_normalize(const float* __restrict__ zi,
                                                   const float* __restrict__ zj,
                                                   __hip_bfloat16* __restrict__ zb,
                                                   float* __restrict__ ps) {
    int w = threadIdx.x >> 6;
    int lane = threadIdx.x & 63;
    int r = blockIdx.x * 4 + w;                       // [0, BATCH)

    float2 vi = *reinterpret_cast<const float2*>(zi + (size_t)r * DIM + lane * 2);
    float2 vj = *reinterpret_cast<const float2*>(zj + (size_t)r * DIM + lane * 2);
    float ssi = vi.x * vi.x + vi.y * vi.y;
    float ssj = vj.x * vj.x + vj.y * vj.y;
    #pragma unroll
    for (int m = 1; m < 64; m <<= 1) {
        ssi += __shfl_xor(ssi, m, 64);
        ssj += __shfl_xor(ssj, m, 64);
    }
    float invi = 1.0f / fmaxf(sqrtf(ssi), 1e-12f);
    float invj = 1.0f / fmaxf(sqrtf(ssj), 1e-12f);

    float nix = vi.x * invi, niy = vi.y * invi;
    float njx = vj.x * invj, njy = vj.y * invj;

    __hip_bfloat162 hi2, hj2;
    hi2.x = __float2bfloat16(nix);
    hi2.y = __float2bfloat16(niy);
    hj2.x = __float2bfloat16(njx);
    hj2.y = __float2bfloat16(njy);
    *reinterpret_cast<__hip_bfloat162*>(zb + (size_t)r * DIM + lane * 2) = hi2;
    *reinterpret_cast<__hip_bfloat162*>(zb + (size_t)(r + BATCH) * DIM + lane * 2) = hj2;

    // paired-diagonal dot in fp32
    float d = nix * njx + niy * njy;
    #pragma unroll
    for (int m = 1; m < 64; m <<= 1) d += __shfl_xor(d, m, 64);

    __shared__ float red[4];
    if (lane == 0) red[w] = d;
    __syncthreads();
    if (threadIdx.x == 0)
        ps[blockIdx.x] = red[0] + red[1] + red[2] + red[3];
}

// ---------------------------------------------------------------------------
// Kernel 2: tiled similarity + fused exp/row partial sums (plain stores).
// Grid: (TWO_B/128) * CS blocks, 256 threads (4 waves, 2x2 wave grid).
// Each block: rows [rowBlk*128, +128), cols [split*1024, +1024) in 8 col-tiles.
// LDS tiles are XOR-swizzled (byte blk16 ^= row&7) to avoid the D=128
// 16-way ds_read_b128 bank conflict (G4).
// Partial row sums go to rs[split*2 + wc][row] (wc = column-half of the wave).
// ---------------------------------------------------------------------------
__global__ __launch_bounds__(256) void k_sim(const __hip_bfloat16* __restrict__ zb,
                                             float* __restrict__ rs) {
    __shared__ unsigned short As[128 * 128];   // 32 KB
    __shared__ unsigned short Bs[128 * 128];   // 32 KB

    const int t = threadIdx.x;
    const int rowBlk = blockIdx.x / CS;
    const int split  = blockIdx.x % CS;
    const int rowBase = rowBlk * 128;

    // ---- stage A tile (reused across all 8 col-tiles) ----
    #pragma unroll
    for (int it = 0; it < 8; ++it) {
        int chunk = t + it * 256;          // 0..2047, each = 16 B
        int row = chunk >> 4;
        int blk = chunk & 15;
        bf16x8 v = *reinterpret_cast<const bf16x8*>(zb + (size_t)(rowBase + row) * DIM + blk * 8);
        int sb = blk ^ (row & 7);
        *reinterpret_cast<bf16x8*>(reinterpret_cast<char*>(As) + row * 256 + sb * 16) = v;
    }

    const int w    = t >> 6;
    const int lane = t & 63;
    const int wr = w >> 1, wc = w & 1;
    const int lo = lane & 15, hi = lane >> 4;

    float psum[4][4];
    #pragma unroll
    for (int i = 0; i < 4; ++i)
        #pragma unroll
        for (int p = 0; p < 4; ++p) psum[i][p] = 0.0f;

    for (int ct = 0; ct < 8; ++ct) {
        const int colBase = split * 1024 + ct * 128;
        __syncthreads();   // prior compute done before overwriting Bs
        #pragma unroll
        for (int it = 0; it < 8; ++it) {
            int chunk = t + it * 256;
            int row = chunk >> 4;
            int blk = chunk & 15;
            bf16x8 v = *reinterpret_cast<const bf16x8*>(zb + (size_t)(colBase + row) * DIM + blk * 8);
            int sb = blk ^ (row & 7);
            *reinterpret_cast<bf16x8*>(reinterpret_cast<char*>(Bs) + row * 256 + sb * 16) = v;
        }
        __syncthreads();

        f32x4 acc[4][4];
        #pragma unroll
        for (int i = 0; i < 4; ++i)
            #pragma unroll
            for (int j = 0; j < 4; ++j) acc[i][j] = (f32x4){0.f, 0.f, 0.f, 0.f};

        #pragma unroll
        for (int ks = 0; ks < 4; ++ks) {
            bf16x8 a[4], b[4];
            #pragma unroll
            for (int i = 0; i < 4; ++i) {
                int rA = wr * 64 + i * 16 + lo;
                int ba = (ks * 4 + hi) ^ (rA & 7);
                a[i] = *reinterpret_cast<const bf16x8*>(
                    reinterpret_cast<const char*>(As) + rA * 256 + ba * 16);
                int rB = wc * 64 + i * 16 + lo;
                int bb = (ks * 4 + hi) ^ (rB & 7);
                b[i] = *reinterpret_cast<const bf16x8*>(
                    reinterpret_cast<const char*>(Bs) + rB * 256 + bb * 16);
            }
            #pragma unroll
            for (int i = 0; i < 4; ++i)
                #pragma unroll
                for (int j = 0; j < 4; ++j)
                    acc[i][j] = __builtin_amdgcn_mfma_f32_16x16x32_bf16(a[i], b[j], acc[i][j], 0, 0, 0);
        }

        // fused epilogue: exp2(acc * EXP_SCALE), exclude self-diagonal, row partials
        // C/D layout (m89): col = lane&15, row = (lane>>4)*4 + reg
        #pragma unroll
        for (int i = 0; i < 4; ++i) {
            int grBase = rowBase + wr * 64 + i * 16 + hi * 4;
            #pragma unroll
            for (int p = 0; p < 4; ++p) {
                int gr = grBase + p;
                float s = 0.0f;
                #pragma unroll
                for (int j = 0; j < 4; ++j) {
                    int gc = colBase + wc * 64 + j * 16 + lo;
                    float e = exp2f(acc[i][j][p] * EXP_SCALE);
                    s += (gr == gc) ? 0.0f : e;
                }
                psum[i][p] += s;
            }
        }
    }

    // reduce across the 16 lanes (lo) holding different columns; plain store.
    #pragma unroll
    for (int i = 0; i < 4; ++i) {
        #pragma unroll
        for (int p = 0; p < 4; ++p) {
            float s = psum[i][p];
            s += __shfl_xor(s, 1, 64);
            s += __shfl_xor(s, 2, 64);
            s += __shfl_xor(s, 4, 64);
            s += __shfl_xor(s, 8, 64);
            if (lo == 0)
                rs[(size_t)(split * 2 + wc) * TWO_B +
                   rowBase + wr * 64 + i * 16 + hi * 4 + p] = s;
        }
    }
}

// ---------------------------------------------------------------------------
// Kernel 3: loss = (sum_r log(sum_c rs[c][r]) - 2*INV_TEMP*possum) / TWO_B
// ---------------------------------------------------------------------------
__global__ __launch_bounds__(1024) void k_final(const float* __restrict__ rs,
                                                const float* __restrict__ ps,
                                                float* __restrict__ out) {
    __shared__ float redl[1024];
    __shared__ float redp[1024];
    const int t = threadIdx.x;

    float s = 0.0f;
    for (int r = t; r < TWO_B; r += 1024) {
        float acc = 0.0f;
        #pragma unroll
        for (int c = 0; c < NPART; ++c) acc += rs[(size_t)c * TWO_B + r];
        s += logf(acc);
    }
    float p = (t < 1024) ? ps[t] : 0.0f;

    redl[t] = s;
    redp[t] = p;
    __syncthreads();
    #pragma unroll
    for (int off = 512; off > 0; off >>= 1) {
        if (t < off) {
            redl[t] += redl[t + off];
            redp[t] += redp[t + off];
        }
        __syncthreads();
    }
    if (t == 0)
        out[0] = (redl[0] - 2.0f * INV_TEMP * redp[0]) / (float)TWO_B;
}

// ---------------------------------------------------------------------------
extern "C" void kernel_launch(void* const* d_in, const int* in_sizes, int n_in,
                              void* d_out, int out_size, void* d_ws, size_t ws_size,
                              hipStream_t stream) {
    const float* zi = (const float*)d_in[0];
    const float* zj = (const float*)d_in[1];
    float* out = (float*)d_out;

    char* ws = (char*)d_ws;
    __hip_bfloat16* zb = (__hip_bfloat16*)ws;
    float* rs = (float*)(ws + RS_OFFSET);
    float* ps = (float*)(ws + PS_OFFSET);

    k_normalize<<<BATCH / 4, 256, 0, stream>>>(zi, zj, zb, ps);
    k_sim<<<(TWO_B / 128) * CS, 256, 0, stream>>>(zb, rs);
    k_final<<<1, 1024, 0, stream>>>(rs, ps, out);
}

// Round 6
// 50.093 us; speedup vs baseline: 2.1060x; 1.0146x over previous
//
#include <hip/hip_runtime.h>
#include <hip/hip_bf16.h>

// Problem constants
#define BATCH   4096
#define TWO_B   8192
#define DIM     128
#define INV_TEMP 2.0f      // 1/TEMP, TEMP=0.5
// sqrt(INV_TEMP * log2(e)) folded into the stored bf16 vectors, so the
// similarity accumulator comes out as sim * INV_TEMP * log2(e) and the
// epilogue is a bare exp2.
#define SFOLD 1.6986436f   // sqrt(2.8853900817779268)

typedef __attribute__((ext_vector_type(8))) short bf16x8;   // 8 bf16 = 4 VGPRs
typedef __attribute__((ext_vector_type(4))) float f32x4;

#define CS 16   // column splits: each wave covers 64 rows x 512 cols

// Workspace layout (bytes):
//   zb     : __hip_bfloat16[TWO_B*DIM]  [0, 2097152)   pre-scaled by SFOLD
//   rowsum : float[TWO_B]               zeroed by k_normalize
//   ps     : float[1024]                per-block possum partials
#define ZB_BYTES   (TWO_B * DIM * 2)
#define RS_OFFSET  ZB_BYTES
#define PS_OFFSET  (RS_OFFSET + TWO_B * 4)

// ---------------------------------------------------------------------------
// Kernel 1: L2-normalize rows of zi AND zj (paired), write bf16 z rows scaled
// by SFOLD, write per-block possum partial, and zero rowsum (8 floats/block).
// ---------------------------------------------------------------------------
__global__ __launch_bounds__(256) void k_normalize(const float* __restrict__ zi,
                                                   const float* __restrict__ zj,
                                                   __hip_bfloat16* __restrict__ zb,
                                                   float* __restrict__ ps,
                                                   float* __restrict__ rowsum) {
    int w = threadIdx.x >> 6;
    int lane = threadIdx.x & 63;
    int r = blockIdx.x * 4 + w;                       // [0, BATCH)

    // zero rowsum: 1024 blocks x 8 floats = 8192
    if (threadIdx.x < 8) rowsum[blockIdx.x * 8 + threadIdx.x] = 0.0f;

    float2 vi = *reinterpret_cast<const float2*>(zi + (size_t)r * DIM + lane * 2);
    float2 vj = *reinterpret_cast<const float2*>(zj + (size_t)r * DIM + lane * 2);
    float ssi = vi.x * vi.x + vi.y * vi.y;
    float ssj = vj.x * vj.x + vj.y * vj.y;
    #pragma unroll
    for (int m = 1; m < 64; m <<= 1) {
        ssi += __shfl_xor(ssi, m, 64);
        ssj += __shfl_xor(ssj, m, 64);
    }
    float invi = 1.0f / fmaxf(sqrtf(ssi), 1e-12f);
    float invj = 1.0f / fmaxf(sqrtf(ssj), 1e-12f);

    float nix = vi.x * invi, niy = vi.y * invi;
    float njx = vj.x * invj, njy = vj.y * invj;

    __hip_bfloat162 hi2, hj2;
    hi2.x = __float2bfloat16(nix * SFOLD);
    hi2.y = __float2bfloat16(niy * SFOLD);
    hj2.x = __float2bfloat16(njx * SFOLD);
    hj2.y = __float2bfloat16(njy * SFOLD);
    *reinterpret_cast<__hip_bfloat162*>(zb + (size_t)r * DIM + lane * 2) = hi2;
    *reinterpret_cast<__hip_bfloat162*>(zb + (size_t)(r + BATCH) * DIM + lane * 2) = hj2;

    // paired-diagonal dot in fp32 (unscaled)
    float d = nix * njx + niy * njy;
    #pragma unroll
    for (int m = 1; m < 64; m <<= 1) d += __shfl_xor(d, m, 64);

    __shared__ float red[4];
    if (lane == 0) red[w] = d;
    __syncthreads();
    if (threadIdx.x == 0)
        ps[blockIdx.x] = red[0] + red[1] + red[2] + red[3];
}

// ---------------------------------------------------------------------------
// Kernel 2: similarity + fused exp2/row-sum. NO LDS, NO barriers.
// Grid: 32 rowBlocks * CS blocks, 256 threads (4 waves). Wave w owns rows
// [rowBlock*256 + w*64, +64); all 4 waves share cols [split*512, +512)
// (8 x 64-col tiles) so B-fragment reads hit L1 after the first wave.
// A-fragments live in registers for the whole kernel (16 x bf16x8).
// MFMA C/D layout (m89): col = lane&15, row = (lane>>4)*4 + reg.
// ---------------------------------------------------------------------------
__global__ __launch_bounds__(256, 2) void k_sim(const __hip_bfloat16* __restrict__ zb,
                                                float* __restrict__ rowsum) {
    const int t = threadIdx.x;
    const int w = t >> 6;
    const int lane = t & 63;
    const int lo = lane & 15, hi = lane >> 4;

    const int rowBlock = blockIdx.x / CS;
    const int split    = blockIdx.x % CS;
    const int rowBase  = rowBlock * 256 + w * 64;

    const char* zbB = reinterpret_cast<const char*>(zb);

    // A fragments: a[i][ks] = 16B at row (rowBase+i*16+lo), k-chunk (ks*4+hi)
    bf16x8 a[4][4];
    #pragma unroll
    for (int i = 0; i < 4; ++i) {
        const char* rp = zbB + (size_t)(rowBase + i * 16 + lo) * 256 + hi * 16;
        #pragma unroll
        for (int ks = 0; ks < 4; ++ks)
            a[i][ks] = *reinterpret_cast<const bf16x8*>(rp + ks * 64);
    }

    float psum[4][4];
    #pragma unroll
    for (int i = 0; i < 4; ++i)
        #pragma unroll
        for (int p = 0; p < 4; ++p) psum[i][p] = 0.0f;

    for (int ct = 0; ct < 8; ++ct) {
        const int colBase = split * 512 + ct * 64;

        // B fragments for this 64-col tile (straight from global; L1-resident
        // for waves 1..3 of the block).
        bf16x8 b[4][4];
        #pragma unroll
        for (int j = 0; j < 4; ++j) {
            const char* rp = zbB + (size_t)(colBase + j * 16 + lo) * 256 + hi * 16;
            #pragma unroll
            for (int ks = 0; ks < 4; ++ks)
                b[j][ks] = *reinterpret_cast<const bf16x8*>(rp + ks * 64);
        }

        f32x4 acc[4][4];
        #pragma unroll
        for (int i = 0; i < 4; ++i)
            #pragma unroll
            for (int j = 0; j < 4; ++j) acc[i][j] = (f32x4){0.f, 0.f, 0.f, 0.f};

        #pragma unroll
        for (int ks = 0; ks < 4; ++ks)
            #pragma unroll
            for (int i = 0; i < 4; ++i)
                #pragma unroll
                for (int j = 0; j < 4; ++j)
                    acc[i][j] = __builtin_amdgcn_mfma_f32_16x16x32_bf16(
                        a[i][ks], b[j][ks], acc[i][j], 0, 0, 0);

        // epilogue: acc already = sim * INV_TEMP * log2(e)  ->  exp2 and sum.
        if (colBase == rowBase) {
            // diagonal tile: element (i,j,p) is the self-sim when j==i and
            // lo == hi*4+p  (gr == gc); exclude it.
            #pragma unroll
            for (int i = 0; i < 4; ++i)
                #pragma unroll
                for (int p = 0; p < 4; ++p) {
                    float s = 0.0f;
                    #pragma unroll
                    for (int j = 0; j < 4; ++j) {
                        float e = exp2f(acc[i][j][p]);
                        if (j == i && lo == hi * 4 + p) e = 0.0f;
                        s += e;
                    }
                    psum[i][p] += s;
                }
        } else {
            #pragma unroll
            for (int i = 0; i < 4; ++i)
                #pragma unroll
                for (int p = 0; p < 4; ++p) {
                    float s = 0.0f;
                    #pragma unroll
                    for (int j = 0; j < 4; ++j) s += exp2f(acc[i][j][p]);
                    psum[i][p] += s;
                }
        }
    }

    // reduce over the 16 lo-lanes (distinct columns) and atomicAdd per row.
    #pragma unroll
    for (int i = 0; i < 4; ++i) {
        #pragma unroll
        for (int p = 0; p < 4; ++p) {
            float s = psum[i][p];
            s += __shfl_xor(s, 1, 64);
            s += __shfl_xor(s, 2, 64);
            s += __shfl_xor(s, 4, 64);
            s += __shfl_xor(s, 8, 64);
            if (lo == 0)
                atomicAdd(&rowsum[rowBase + i * 16 + hi * 4 + p], s);
        }
    }
}

// ---------------------------------------------------------------------------
// Kernel 3: loss = (sum_r log(rowsum[r]) - 2*INV_TEMP*possum) / TWO_B
// ---------------------------------------------------------------------------
__global__ __launch_bounds__(1024) void k_final(const float* __restrict__ rowsum,
                                                const float* __restrict__ ps,
                                                float* __restrict__ out) {
    __shared__ float redl[1024];
    __shared__ float redp[1024];
    const int t = threadIdx.x;

    float s = 0.0f;
    #pragma unroll
    for (int q = 0; q < TWO_B / 1024; ++q) s += logf(rowsum[t + q * 1024]);
    float p = ps[t];

    redl[t] = s;
    redp[t] = p;
    __syncthreads();
    #pragma unroll
    for (int off = 512; off > 0; off >>= 1) {
        if (t < off) {
            redl[t] += redl[t + off];
            redp[t] += redp[t + off];
        }
        __syncthreads();
    }
    if (t == 0)
        out[0] = (redl[0] - 2.0f * INV_TEMP * redp[0]) / (float)TWO_B;
}

// ---------------------------------------------------------------------------
extern "C" void kernel_launch(void* const* d_in, const int* in_sizes, int n_in,
                              void* d_out, int out_size, void* d_ws, size_t ws_size,
                              hipStream_t stream) {
    const float* zi = (const float*)d_in[0];
    const float* zj = (const float*)d_in[1];
    float* out = (float*)d_out;

    char* ws = (char*)d_ws;
    __hip_bfloat16* zb = (__hip_bfloat16*)ws;
    float* rowsum = (float*)(ws + RS_OFFSET);
    float* ps = (float*)(ws + PS_OFFSET);

    k_normalize<<<BATCH / 4, 256, 0, stream>>>(zi, zj, zb, ps, rowsum);
    k_sim<<<(TWO_B / 256) * CS, 256, 0, stream>>>(zb, rowsum);
    k_final<<<1, 1024, 0, stream>>>(rowsum, ps, out);
}